// Round 2
// baseline (176.150 us; speedup 1.0000x reference)
//
#include <hip/hip_runtime.h>
#include <cstddef>

constexpr int BH = 32;    // batch*heads
constexpr int N  = 8192;  // sequence
constexpr int D  = 64;    // dim
constexpr int BK = 64;    // bucket size
constexpr int NB = 128;   // N / BK buckets
constexpr int NC = 129;   // NB + 1 (padded sk)

// ---------------------------------------------------------------------------
// Kernel A (barrier-free): wave-per-bucket. Lane layout: f = lane&15 (float4
// column), r0 = lane>>4 (row group of 16 contiguous rows). Each thread sweeps
// its 16 rows DESCENDING, accumulating the suffix-harmonic weight wh
// incrementally, so tailw needs no LDS/precompute. Cross-group tail fixed up
// via kw += TU*ksum with 3 shuffles; reduction over r0 = 2 shuffle-xor steps.
// ---------------------------------------------------------------------------
__global__ __launch_bounds__(256) void kA(const float* __restrict__ q,
                                          const float* __restrict__ k,
                                          float* __restrict__ qsum,
                                          float* __restrict__ ksum,
                                          float* __restrict__ kw,
                                          float* __restrict__ qfirst,
                                          float* __restrict__ W) {
  const int tid  = threadIdx.x;
  const int wv   = tid >> 6;
  const int lane = tid & 63;
  const int f    = lane & 15;
  const int r0   = lane >> 4;          // 0..3 (16 rows each)
  const int j    = blockIdx.x * 4 + wv;
  const int b    = blockIdx.y;
  const int base = j * BK;

  const float4* q4 = (const float4*)(q + ((size_t)b * N + base) * D);
  const float4* k4 = (const float4*)(k + ((size_t)b * N + base) * D);

  float aq[4] = {0,0,0,0}, ak[4] = {0,0,0,0}, aw[4] = {0,0,0,0};
  float qf[4] = {0,0,0,0};
  float wh = 0.0f;  // suffix harmonic within this thread's 16-row strip

#pragma unroll
  for (int t = 15; t >= 0; --t) {
    const int row = (r0 << 4) + t;
    wh += 1.0f / (float)(base + row + 1);   // include own row first (suffix incl.)
    const float4 qv = q4[row * 16 + f];
    const float4 kv = k4[row * 16 + f];
    aq[0] += qv.x; aq[1] += qv.y; aq[2] += qv.z; aq[3] += qv.w;
    ak[0] += kv.x; ak[1] += kv.y; ak[2] += kv.z; ak[3] += kv.w;
    aw[0] += kv.x * wh; aw[1] += kv.y * wh; aw[2] += kv.z * wh; aw[3] += kv.w * wh;
    if (t == 0 && r0 == 0) { qf[0] = qv.x; qf[1] = qv.y; qf[2] = qv.z; qf[3] = qv.w; }
  }

  // strip harmonic sums of all 4 row-groups (same f, different r0)
  const float w16 = __shfl_xor(wh, 16);
  const float w32 = __shfl_xor(wh, 32);
  const float w48 = __shfl_xor(wh, 48);
  float TU = 0.0f;                        // tail = sum of strips ABOVE r0
  if ((r0 ^ 1) > r0) TU += w16;
  if ((r0 ^ 2) > r0) TU += w32;
  if ((r0 ^ 3) > r0) TU += w48;
  const float Wfull = wh + w16 + w32 + w48;

#pragma unroll
  for (int c = 0; c < 4; ++c) aw[c] += TU * ak[c];   // before reduction!

#pragma unroll
  for (int c = 0; c < 4; ++c) {
    aq[c] += __shfl_xor(aq[c], 16); aq[c] += __shfl_xor(aq[c], 32);
    ak[c] += __shfl_xor(ak[c], 16); ak[c] += __shfl_xor(ak[c], 32);
    aw[c] += __shfl_xor(aw[c], 16); aw[c] += __shfl_xor(aw[c], 32);
  }

  if (r0 == 0) {
    const size_t ob = ((size_t)b * NB + j) * D;
    ((float4*)(qsum   + ob))[f] = make_float4(aq[0], aq[1], aq[2], aq[3]);
    ((float4*)(ksum   + ob))[f] = make_float4(ak[0], ak[1], ak[2], ak[3]);
    ((float4*)(kw     + ob))[f] = make_float4(aw[0], aw[1], aw[2], aw[3]);
    ((float4*)(qfirst + ob))[f] = make_float4(qf[0], qf[1], qf[2], qf[3]);
    if (f == 0 && b == 0) W[j] = Wfull;
  }
}

// ---------------------------------------------------------------------------
// Kernel B: prefix scan. grid (2, BH): x=0 -> q side (sq), x=1 -> k side (skp).
// Stage the scanned array in LDS (coalesced float4), scan from LDS so the
// serial chain is pure FMA + conflict-free LDS reads.
// ---------------------------------------------------------------------------
__global__ __launch_bounds__(256) void kB(const float* __restrict__ qsum,
                                          const float* __restrict__ ksum,
                                          const float* __restrict__ kw,
                                          const float* __restrict__ qfirst,
                                          const float* __restrict__ W,
                                          float* __restrict__ sq,
                                          float* __restrict__ skp) {
  const int side = blockIdx.x;   // 0: q, 1: k
  const int b    = blockIdx.y;
  const int tid  = threadIdx.x;
  const int d    = tid & 63;
  const int jg   = tid >> 6;     // 0..3

  __shared__ float buf[NB * D];  // 32 KB
  __shared__ float tot[4 * D];   // 1 KB
  __shared__ float Wl[NB];       // 0.5 KB

  const float* src = (side == 0 ? qsum : ksum) + (size_t)b * NB * D;
  {
    const float4* g4 = (const float4*)src;
    float4* l4 = (float4*)buf;
    for (int u = tid; u < NB * D / 4; u += 256) l4[u] = g4[u];
    if (side == 1 && tid < NB) Wl[tid] = W[tid];
  }
  __syncthreads();

  float t0 = 0.0f;
  for (int jj = 0; jj < 32; ++jj) t0 += buf[(jg * 32 + jj) * D + d];
  tot[jg * D + d] = t0;
  __syncthreads();

  float pre = 0.0f;
  for (int g = 0; g < jg; ++g) pre += tot[g * D + d];

  if (side == 0) {
    for (int jj = 0; jj < 32; ++jj) {
      const int j = jg * 32 + jj;
      const size_t o = ((size_t)b * NB + j) * D + d;
      sq[o] = (pre + qfirst[o]) / (float)(j * BK + 1);
      pre += buf[j * D + d];
    }
  } else {
    if (tid < D) skp[(size_t)b * NC * D + tid] = 0.0f;  // pad row 0
    for (int jj = 0; jj < 32; ++jj) {
      const int j = jg * 32 + jj;
      const size_t o = ((size_t)b * NB + j) * D + d;
      skp[((size_t)b * NC + j + 1) * D + d] = pre * Wl[j] + kw[o];
      pre += buf[j * D + d];
    }
  }
}

// ---------------------------------------------------------------------------
// Kernel C: one (b,i) row per 128-thread block (col 128 is always masked so
// it never needs a dot). Wave shuffle reductions + 2-element LDS combine.
// ---------------------------------------------------------------------------
__global__ __launch_bounds__(128) void kC(const float* __restrict__ sq,
                                          const float* __restrict__ skp,
                                          float* __restrict__ out) {
  const int i   = blockIdx.x;
  const int b   = blockIdx.y;
  const int tid = threadIdx.x;
  const int wv  = tid >> 6;

  __shared__ float srow[D];
  __shared__ float wred[2][2];

  if (tid < 16)
    ((float4*)srow)[tid] = ((const float4*)(sq + ((size_t)b * NB + i) * D))[tid];
  __syncthreads();

  const int j = tid;
  const bool valid = (j <= i);
  float dot = 0.0f;
  if (valid) {
    const float4* kr = (const float4*)(skp + ((size_t)b * NC + j) * D);
    const float4* sr = (const float4*)srow;
#pragma unroll
    for (int f = 0; f < 16; ++f) {
      const float4 a = sr[f];
      const float4 c = kr[f];
      dot += a.x * c.x + a.y * c.y + a.z * c.z + a.w * c.w;
    }
    dot *= 0.125f;
  }

  float m = valid ? dot : -3.402823466e38f;
#pragma unroll
  for (int s = 32; s; s >>= 1) m = fmaxf(m, __shfl_xor(m, s));
  if ((tid & 63) == 0) wred[0][wv] = m;
  __syncthreads();
  const float mx = fmaxf(wred[0][0], wred[0][1]);

  const float e = valid ? expf(dot - mx) : 0.0f;
  float ss = e;
#pragma unroll
  for (int s = 32; s; s >>= 1) ss += __shfl_xor(ss, s);
  if ((tid & 63) == 0) wred[1][wv] = ss;
  __syncthreads();
  const float denom = wred[1][0] + wred[1][1];

  float* orow = out + ((size_t)b * NB + i) * NC;
  orow[j] = (j < i) ? (e / denom) : 0.0f;
  if (tid == 0) orow[128] = 0.0f;
}

// ---------------------------------------------------------------------------
extern "C" void kernel_launch(void* const* d_in, const int* in_sizes, int n_in,
                              void* d_out, int out_size, void* d_ws, size_t ws_size,
                              hipStream_t stream) {
  const float* q = (const float*)d_in[0];
  const float* k = (const float*)d_in[1];
  float* out = (float*)d_out;

  float* ws     = (float*)d_ws;
  float* qsum   = ws;                      // BH*NB*D
  float* ksum   = qsum   + (size_t)BH * NB * D;
  float* kw     = ksum   + (size_t)BH * NB * D;
  float* qfirst = kw     + (size_t)BH * NB * D;
  float* sq     = qfirst + (size_t)BH * NB * D;
  float* skp    = sq     + (size_t)BH * NB * D;  // BH*NC*D
  float* W      = skp    + (size_t)BH * NC * D;  // NB

  kA<<<dim3(NB / 4, BH), 256, 0, stream>>>(q, k, qsum, ksum, kw, qfirst, W);
  kB<<<dim3(2, BH), 256, 0, stream>>>(qsum, ksum, kw, qfirst, W, sq, skp);
  kC<<<dim3(NB, BH), 128, 0, stream>>>(sq, skp, out);
}

// Round 3
// 158.829 us; speedup vs baseline: 1.1091x; 1.1091x over previous
//
#include <hip/hip_runtime.h>
#include <cstddef>

constexpr int BH = 32;    // batch*heads
constexpr int N  = 8192;  // sequence
constexpr int D  = 64;    // dim
constexpr int BK = 64;    // bucket size
constexpr int NB = 128;   // N / BK buckets
constexpr int NC = 129;   // NB + 1 (padded sk)

// ---------------------------------------------------------------------------
// Kernel A: one block per (bucket j, b, side). side 0: q -> qsum + qfirst.
// side 1: k -> ksum + kw (suffix-harmonic weighted). 4 independent float4
// loads per thread, shuffle reduce + one LDS combine. 8192 blocks.
// ---------------------------------------------------------------------------
__global__ __launch_bounds__(256) void kA(const float* __restrict__ q,
                                          const float* __restrict__ k,
                                          float* __restrict__ qsum,
                                          float* __restrict__ ksum,
                                          float* __restrict__ kw,
                                          float* __restrict__ qfirst,
                                          float* __restrict__ W) {
  const int j = blockIdx.x, b = blockIdx.y, side = blockIdx.z;
  const int tid = threadIdx.x;
  const int f = tid & 15, r = tid >> 4, w = tid >> 6, lane = tid & 63;
  const int base = j * BK;

  __shared__ float tailw[BK];
  __shared__ float red[2][4][D];

  const float* src = (side == 0 ? q : k) + ((size_t)b * N + base) * D;
  const float4* s4 = (const float4*)src;

  // 4 independent loads, issued before any barrier
  float4 v[4];
#pragma unroll
  for (int p = 0; p < 4; ++p) v[p] = s4[(r + 16 * p) * 16 + f];

  if (side == 1) {
    if (w == 0) {
      float x = 1.0f / (float)(base + lane + 1);
#pragma unroll
      for (int s = 1; s < 64; s <<= 1) {
        float y = __shfl_down(x, s, 64);
        if (lane + s < 64) x += y;
      }
      tailw[lane] = x;                       // suffix harmonic within bucket
      if (lane == 0 && b == 0) W[j] = x;     // full-bucket harmonic
    }
    __syncthreads();
  }

  float a0[4] = {0, 0, 0, 0}, a1[4] = {0, 0, 0, 0};
  if (side == 0) {
#pragma unroll
    for (int p = 0; p < 4; ++p) {
      a0[0] += v[p].x; a0[1] += v[p].y; a0[2] += v[p].z; a0[3] += v[p].w;
    }
  } else {
#pragma unroll
    for (int p = 0; p < 4; ++p) {
      const float tw = tailw[r + 16 * p];
      a0[0] += v[p].x; a0[1] += v[p].y; a0[2] += v[p].z; a0[3] += v[p].w;
      a1[0] += v[p].x * tw; a1[1] += v[p].y * tw;
      a1[2] += v[p].z * tw; a1[3] += v[p].w * tw;
    }
  }

  // in-wave reduce over the 4 row-groups resident in this wave
#pragma unroll
  for (int c = 0; c < 4; ++c) {
    a0[c] += __shfl_xor(a0[c], 16, 64); a0[c] += __shfl_xor(a0[c], 32, 64);
    a1[c] += __shfl_xor(a1[c], 16, 64); a1[c] += __shfl_xor(a1[c], 32, 64);
  }
  if (lane < 16) {  // lane == f
    ((float4*)&red[0][w][0])[f] = make_float4(a0[0], a0[1], a0[2], a0[3]);
    ((float4*)&red[1][w][0])[f] = make_float4(a1[0], a1[1], a1[2], a1[3]);
  }
  __syncthreads();

  const size_t ob = ((size_t)b * NB + j) * D;
  if (tid < D) {
    const float s0 = red[0][0][tid] + red[0][1][tid] + red[0][2][tid] + red[0][3][tid];
    if (side == 0) {
      qsum[ob + tid] = s0;
    } else {
      ksum[ob + tid] = s0;
      kw[ob + tid] = red[1][0][tid] + red[1][1][tid] + red[1][2][tid] + red[1][3][tid];
    }
  }
  if (side == 0 && r == 0) {  // this thread's first load is bucket row 0
    ((float4*)(qfirst + ob))[f] = v[0];
  }
}

// ---------------------------------------------------------------------------
// Kernel BC (fused scan + scores + softmax): one block per (b, 16-row i-tile).
// Recomputes the bucket prefix scans from LDS (cheap, removes the sq/skp
// global round-trip + one dispatch). skp stored XOR-swizzled in LDS:
// row jc, float4 slot (d4 + jc) & 15 -> conflict-free b128 reads in dot phase.
// Column jc=128 is always masked (128 > i for all i <= 127) -> never computed.
// ---------------------------------------------------------------------------
__global__ __launch_bounds__(256) void kBC(const float* __restrict__ qsum,
                                           const float* __restrict__ ksum,
                                           const float* __restrict__ kw,
                                           const float* __restrict__ qfirst,
                                           const float* __restrict__ W,
                                           float* __restrict__ out) {
  const int tile = blockIdx.x, b = blockIdx.y;
  const int tid = threadIdx.x;
  const int d = tid & 63, g = tid >> 6;
  const int jp = tid & 63, rep = tid >> 6;

  __shared__ float buf[NB * D];    // 32 KB (qsum, then ksum)
  __shared__ float skpS[NB * D];   // 32 KB swizzled (rows 0..127 of padded sk)
  __shared__ float sqs[16 * D];    // 4 KB
  __shared__ float tots[4 * D];
  __shared__ float Wl[NB];

  const size_t bb = (size_t)b * NB * D;

  // ---- stage: qsum -> buf, qfirst tile -> sqs, W, kw -> skpS rows 1..127
  {
    const float4* g4 = (const float4*)(qsum + bb);
    float4* l4 = (float4*)buf;
    for (int u = tid; u < NB * D / 4; u += 256) l4[u] = g4[u];

    const float4* qf4 = (const float4*)(qfirst + bb + (size_t)tile * 16 * D);
    float4* sq4 = (float4*)sqs;
    sq4[tid] = qf4[tid];  // 16*64/4 == 256

    if (tid < NB) Wl[tid] = W[tid];

    const float4* kw4 = (const float4*)(kw + bb);
    for (int u = tid; u < 127 * 16; u += 256) {
      const int row = (u >> 4) + 1, f = u & 15;
      ((float4*)skpS)[row * 16 + ((f + row) & 15)] = kw4[u];
    }
    if (tid < D) skpS[tid] = 0.0f;  // row 0 (identity swizzle)
  }
  __syncthreads();

  const int T0 = tile * 16;
  // ---- q-scan: prefix over [0, T0) split 4 ways, then 16 serial in-tile steps
  {
    const int span = T0 >> 2;
    float t0 = 0.0f;
    for (int jj = g * span; jj < (g + 1) * span; ++jj) t0 += buf[jj * D + d];
    tots[g * D + d] = t0;
  }
  __syncthreads();
  if (tid < D) {
    float pre = tots[d] + tots[D + d] + tots[2 * D + d] + tots[3 * D + d];
    for (int ii = 0; ii < 16; ++ii) {
      const int i = T0 + ii;
      sqs[ii * D + d] = (pre + sqs[ii * D + d]) / (float)(i * BK + 1);
      pre += buf[i * D + d];
    }
  }
  __syncthreads();

  // ---- ksum -> buf
  {
    const float4* g4 = (const float4*)(ksum + bb);
    float4* l4 = (float4*)buf;
    for (int u = tid; u < NB * D / 4; u += 256) l4[u] = g4[u];
  }
  __syncthreads();
  {
    float t0 = 0.0f;
    for (int jj = g * 32; jj < (g + 1) * 32; ++jj) t0 += buf[jj * D + d];
    tots[g * D + d] = t0;
  }
  __syncthreads();
  {
    float pre = 0.0f;
    for (int gg = 0; gg < g; ++gg) pre += tots[gg * D + d];
    for (int jj = 0; jj < 32; ++jj) {
      const int j = g * 32 + jj;
      if (j < 127) {  // skp row 128 never needed
        const int row = j + 1;
        const int idx = row * D + (((d >> 2) + row) & 15) * 4 + (d & 3);
        skpS[idx] = pre * Wl[j] + skpS[idx];
      }
      pre += buf[j * D + d];
    }
  }
  __syncthreads();

  // ---- dots: thread = (jp, rep) owns cols {jp, jp+64}, rows {rep*4..rep*4+3}
  float acc0[4] = {0, 0, 0, 0}, acc1[4] = {0, 0, 0, 0};
  const float4* sk4 = (const float4*)skpS;
  const float4* sq4 = (const float4*)sqs;
#pragma unroll
  for (int d4 = 0; d4 < 16; ++d4) {
    const int slot = (d4 + jp) & 15;        // same slot for jp and jp+64
    const float4 k0 = sk4[jp * 16 + slot];
    const float4 k1 = sk4[(jp + 64) * 16 + slot];
#pragma unroll
    for (int ii = 0; ii < 4; ++ii) {
      const float4 s = sq4[(rep * 4 + ii) * 16 + d4];
      acc0[ii] += s.x * k0.x + s.y * k0.y + s.z * k0.z + s.w * k0.w;
      acc1[ii] += s.x * k1.x + s.y * k1.y + s.z * k1.z + s.w * k1.w;
    }
  }

  // ---- softmax (in-wave: row i's 128 cols live across this wave) + store
#pragma unroll
  for (int ii = 0; ii < 4; ++ii) {
    const int i = T0 + rep * 4 + ii;
    const int j0 = jp, j1 = jp + 64;
    const float v0 = acc0[ii] * 0.125f, v1 = acc1[ii] * 0.125f;
    const bool val0 = (j0 <= i), val1 = (j1 <= i);
    float m = fmaxf(val0 ? v0 : -3.402823466e38f, val1 ? v1 : -3.402823466e38f);
#pragma unroll
    for (int s = 1; s < 64; s <<= 1) m = fmaxf(m, __shfl_xor(m, s, 64));
    const float e0 = val0 ? __expf(v0 - m) : 0.0f;
    const float e1 = val1 ? __expf(v1 - m) : 0.0f;
    float ss = e0 + e1;
#pragma unroll
    for (int s = 1; s < 64; s <<= 1) ss += __shfl_xor(ss, s, 64);
    const float rden = 1.0f / ss;
    float* orow = out + ((size_t)b * NB + i) * NC;
    orow[j0] = (j0 < i) ? e0 * rden : 0.0f;
    orow[j1] = (j1 < i) ? e1 * rden : 0.0f;
    if (jp == 0) orow[128] = 0.0f;
  }
}

// ---------------------------------------------------------------------------
extern "C" void kernel_launch(void* const* d_in, const int* in_sizes, int n_in,
                              void* d_out, int out_size, void* d_ws, size_t ws_size,
                              hipStream_t stream) {
  const float* q = (const float*)d_in[0];
  const float* k = (const float*)d_in[1];
  float* out = (float*)d_out;

  float* ws     = (float*)d_ws;
  float* qsum   = ws;                          // BH*NB*D
  float* ksum   = qsum   + (size_t)BH * NB * D;
  float* kw     = ksum   + (size_t)BH * NB * D;
  float* qfirst = kw     + (size_t)BH * NB * D;
  float* W      = qfirst + (size_t)BH * NB * D;  // NB

  kA<<<dim3(NB, BH, 2), 256, 0, stream>>>(q, k, qsum, ksum, kw, qfirst, W);
  kBC<<<dim3(8, BH), 256, 0, stream>>>(qsum, ksum, kw, qfirst, W, out);
}